// Round 1
// baseline (829.080 us; speedup 1.0000x reference)
//
#include <hip/hip_runtime.h>
#include <hip/hip_fp16.h>
#include <math.h>

// Problem constants (fixed by the reference): B=4, L=1024, D=512, H=8, d=64
#define L_ 1024
#define D_ 512
#define H_ 8
#define TL 4   // query rows per block

// LDS score tile: sln[m][ 4*(h ^ (m&7)) + r ]  (fp16, XOR-swizzled cols) = 64 KB
// Column quad for a given h holds r=0..3 contiguously (8B) -> half2/b64 access.

__global__ __launch_bounds__(256) void attn_main(
    const float* __restrict__ Kp, const float* __restrict__ Qp,
    const float* __restrict__ Vp, const float* __restrict__ doc,
    const float* __restrict__ gamma, const float* __restrict__ beta,
    float* __restrict__ out, float* __restrict__ wacc)
{
    __shared__ __half sln[L_][32];   // 65536 bytes

    const int t   = threadIdx.x;
    const int b   = blockIdx.x & 3;        // XCD-locality: same XCD -> same b
    const int lt  = blockIdx.x >> 2;
    const int l0  = lt * TL;
    const int len = (int)doc[b];

    // ---------------- phase 1: raw scores s[r][h][m] = K[b,l0+r,h,:].Q[b,m,h,:]
    {
        const int h  = t & 7;
        const int mi = t >> 3;                 // 0..31
        const float4* Q4 = (const float4*)Qp + (size_t)b * L_ * 128;
        const float4* K4 = (const float4*)Kp + (size_t)b * L_ * 128;
        const int cb = 4 * (h ^ (mi & 7));     // m&7 == mi&7 for all our m

        for (int tile = 0; tile < 8; ++tile) {
            float acc[TL][4];
            #pragma unroll
            for (int r = 0; r < TL; ++r)
                #pragma unroll
                for (int mj = 0; mj < 4; ++mj) acc[r][mj] = 0.f;

            const int mbase = tile * 128 + mi;     // m = mbase + mj*32
            for (int d4 = 0; d4 < 16; ++d4) {
                float4 kv[TL];
                #pragma unroll
                for (int r = 0; r < TL; ++r)
                    kv[r] = K4[(size_t)(l0 + r) * 128 + h * 16 + d4];
                #pragma unroll
                for (int mj = 0; mj < 4; ++mj) {
                    float4 qv = Q4[(size_t)(mbase + mj * 32) * 128 + h * 16 + d4];
                    #pragma unroll
                    for (int r = 0; r < TL; ++r)
                        acc[r][mj] += qv.x * kv[r].x + qv.y * kv[r].y
                                    + qv.z * kv[r].z + qv.w * kv[r].w;
                }
            }
            #pragma unroll
            for (int mj = 0; mj < 4; ++mj) {
                const int m = mbase + mj * 32;
                *(__half2*)&sln[m][cb]     = __floats2half2_rn(acc[0][mj], acc[1][mj]);
                *(__half2*)&sln[m][cb + 2] = __floats2half2_rn(acc[2][mj], acc[3][mj]);
            }
        }
    }
    __syncthreads();

    // ---------------- phase 2: LayerNorm over heads + pad mask (-inf)
    {
        float g[8], be[8];
        #pragma unroll
        for (int hh = 0; hh < 8; ++hh) { g[hh] = gamma[hh]; be[hh] = beta[hh]; }

        #pragma unroll
        for (int i = 0; i < 4; ++i) {
            const int m  = t + 256 * i;
            const int sw = m & 7;
            float v[8][4];
            #pragma unroll
            for (int hh = 0; hh < 8; ++hh) {
                const int cb = 4 * (hh ^ sw);
                __half2 lo = *(const __half2*)&sln[m][cb];
                __half2 hi = *(const __half2*)&sln[m][cb + 2];
                v[hh][0] = __low2float(lo);  v[hh][1] = __high2float(lo);
                v[hh][2] = __low2float(hi);  v[hh][3] = __high2float(hi);
            }
            const bool mvalid = (m < len);
            #pragma unroll
            for (int r = 0; r < 4; ++r) {
                float mu = 0.f;
                #pragma unroll
                for (int hh = 0; hh < 8; ++hh) mu += v[hh][r];
                mu *= 0.125f;
                float var = 0.f;
                #pragma unroll
                for (int hh = 0; hh < 8; ++hh) { float dd = v[hh][r] - mu; var += dd * dd; }
                var *= 0.125f;
                const float rs = 1.0f / sqrtf(var + 1e-5f);
                const bool keep = mvalid && ((l0 + r) < len);
                #pragma unroll
                for (int hh = 0; hh < 8; ++hh)
                    v[hh][r] = keep ? ((v[hh][r] - mu) * rs * g[hh] + be[hh]) : -INFINITY;
            }
            #pragma unroll
            for (int hh = 0; hh < 8; ++hh) {
                const int cb = 4 * (hh ^ sw);
                *(__half2*)&sln[m][cb]     = __floats2half2_rn(v[hh][0], v[hh][1]);
                *(__half2*)&sln[m][cb + 2] = __floats2half2_rn(v[hh][2], v[hh][3]);
            }
        }
    }
    __syncthreads();

    // ---------------- phase 3: per-wave softmax over m; convert s -> p; accumulate w
    // wave w owns heads {2w, 2w+1}; pair p = (hh_sub<<2)|r; 8 lanes (j) per pair.
    {
        const int wv   = t >> 6;
        const int lane = t & 63;
        const int p    = lane >> 3;           // 0..7
        const int j    = lane & 7;
        const int r    = p & 3;
        const int hh   = 2 * wv + (p >> 2);
        const int pcol = 4 * (hh ^ j) + r;    // m&7 == j along our m-walk

        float mx = -INFINITY;
        for (int i = 0; i < 128; ++i)
            mx = fmaxf(mx, __half2float(sln[j + 8 * i][pcol]));
        mx = fmaxf(mx, __shfl_xor(mx, 1));
        mx = fmaxf(mx, __shfl_xor(mx, 2));
        mx = fmaxf(mx, __shfl_xor(mx, 4));

        float sm = 0.f;
        for (int i = 0; i < 128; ++i) {
            float sv = __half2float(sln[j + 8 * i][pcol]);
            if (sv != -INFINITY) sm += __expf(sv - mx);
        }
        sm += __shfl_xor(sm, 1);
        sm += __shfl_xor(sm, 2);
        sm += __shfl_xor(sm, 4);
        const float inv = (sm > 0.f) ? 1.0f / sm : 0.f;

        for (int i = 0; i < 128; ++i) {
            const int m = j + 8 * i;
            float sv = __half2float(sln[m][pcol]);
            float pe = (sv != -INFINITY) ? __expf(sv - mx) * inv : 0.f;
            sln[m][pcol] = __float2half(pe);
            // sum over this wave's 8 (r,h) pairs at fixed m (lanes with equal j)
            float wc = pe;
            wc += __shfl_xor(wc, 8);
            wc += __shfl_xor(wc, 16);
            wc += __shfl_xor(wc, 32);
            if (p == 0) atomicAdd(&wacc[b * L_ + m], wc);
        }
    }
    __syncthreads();

    // ---------------- phase 4: out[b,l0+r,h*64+d] = sum_m p * V[b,m,h*64+d]
    {
        const int h  = t >> 5;
        const int dl = t & 31;                 // covers d = 2*dl, 2*dl+1
        const float2* V2 = (const float2*)Vp + (size_t)b * L_ * 256;
        float ax0=0,ay0=0, ax1=0,ay1=0, ax2=0,ay2=0, ax3=0,ay3=0;
        #pragma unroll 4
        for (int m = 0; m < L_; ++m) {
            const int cb = 4 * (h ^ (m & 7));
            __half2 lo = *(const __half2*)&sln[m][cb];
            __half2 hi = *(const __half2*)&sln[m][cb + 2];
            const float2 vv = V2[(size_t)m * 256 + h * 32 + dl];
            float p0 = __low2float(lo), p1 = __high2float(lo);
            float p2 = __low2float(hi), p3 = __high2float(hi);
            ax0 += p0 * vv.x; ay0 += p0 * vv.y;
            ax1 += p1 * vv.x; ay1 += p1 * vv.y;
            ax2 += p2 * vv.x; ay2 += p2 * vv.y;
            ax3 += p3 * vv.x; ay3 += p3 * vv.y;
        }
        float2* O2 = (float2*)out;
        const size_t ob = (size_t)b * L_ + l0;
        O2[(ob + 0) * 256 + h * 32 + dl] = make_float2(ax0, ay0);
        O2[(ob + 1) * 256 + h * 32 + dl] = make_float2(ax1, ay1);
        O2[(ob + 2) * 256 + h * 32 + dl] = make_float2(ax2, ay2);
        O2[(ob + 3) * 256 + h * 32 + dl] = make_float2(ax3, ay3);
    }
}

// ---------------- w finalize: w = softmax_m( (wacc/8)/len ), invalid -> 0
__global__ __launch_bounds__(256) void w_final(
    const float* __restrict__ wacc, const float* __restrict__ doc,
    float* __restrict__ wout)
{
    const int b = blockIdx.x;
    const int t = threadIdx.x;
    __shared__ float red[4];

    const float ds = doc[b];
    const int len  = (int)ds;

    float v[4];
    float mx = -INFINITY;
    #pragma unroll
    for (int i = 0; i < 4; ++i) {
        const int m = t + 256 * i;
        const float raw = wacc[b * L_ + m];
        v[i] = (m < len) ? (raw * 0.125f) / ds : -INFINITY;
        mx = fmaxf(mx, v[i]);
    }
    #pragma unroll
    for (int off = 1; off < 64; off <<= 1) mx = fmaxf(mx, __shfl_xor(mx, off));
    if ((t & 63) == 0) red[t >> 6] = mx;
    __syncthreads();
    mx = fmaxf(fmaxf(red[0], red[1]), fmaxf(red[2], red[3]));

    float e[4];
    float sm = 0.f;
    #pragma unroll
    for (int i = 0; i < 4; ++i) {
        e[i] = (v[i] != -INFINITY) ? __expf(v[i] - mx) : 0.f;
        sm += e[i];
    }
    #pragma unroll
    for (int off = 1; off < 64; off <<= 1) sm += __shfl_xor(sm, off);
    __syncthreads();
    if ((t & 63) == 0) red[t >> 6] = sm;
    __syncthreads();
    sm = red[0] + red[1] + red[2] + red[3];
    const float inv = (sm > 0.f) ? 1.0f / sm : 0.f;

    #pragma unroll
    for (int i = 0; i < 4; ++i)
        wout[b * L_ + t + 256 * i] = e[i] * inv;
}

extern "C" void kernel_launch(void* const* d_in, const int* in_sizes, int n_in,
                              void* d_out, int out_size, void* d_ws, size_t ws_size,
                              hipStream_t stream)
{
    const float* K     = (const float*)d_in[0];
    const float* Q     = (const float*)d_in[1];
    const float* V     = (const float*)d_in[2];
    const float* doc   = (const float*)d_in[3];
    const float* gamma = (const float*)d_in[4];
    const float* beta  = (const float*)d_in[5];
    // d_in[6] (pad_mask) and d_in[7] (bx_packed) are derivable from doc_sizes.

    float* out  = (float*)d_out;
    float* wout = out + (size_t)4 * L_ * D_;   // second output, [B,L,1]
    float* wacc = (float*)d_ws;                // 4*1024 floats accumulator

    hipMemsetAsync(wacc, 0, (size_t)4 * L_ * sizeof(float), stream);
    attn_main<<<dim3(1024), dim3(256), 0, stream>>>(K, Q, V, doc, gamma, beta, out, wacc);
    w_final<<<dim3(4), dim3(256), 0, stream>>>(wacc, doc, wout);
}

// Round 2
// 207.890 us; speedup vs baseline: 3.9881x; 3.9881x over previous
//
#include <hip/hip_runtime.h>
#include <math.h>

// B=4, L=1024, D=512, H=8, d=64
#define L_ 1024
#define D_ 512

typedef _Float16 half8 __attribute__((ext_vector_type(8)));
typedef _Float16 half4v __attribute__((ext_vector_type(4)));
typedef float floatx4 __attribute__((ext_vector_type(4)));

// ---------- prep: K,Q -> fp16 straight; V -> fp16 transposed Vt[b][h][d][m]
__global__ __launch_bounds__(256) void prep(
    const float* __restrict__ K, const float* __restrict__ Q,
    const float* __restrict__ V,
    _Float16* __restrict__ K16, _Float16* __restrict__ Q16,
    _Float16* __restrict__ Vt)
{
    __shared__ _Float16 tile[64][72];
    const int t = threadIdx.x;
    const int bi = blockIdx.x;
    if (bi < 256) {
        // 1M float4: first 512k = K, next 512k = Q
        for (int it = 0; it < 16; ++it) {
            size_t f = (size_t)bi * 4096 + it * 256 + t;
            const float4* src; _Float16* dst;
            if (f < 524288) { src = (const float4*)K; dst = K16; }
            else            { src = (const float4*)Q; dst = Q16; f -= 524288; }
            float4 v = src[f];
            half4v h = { (_Float16)v.x, (_Float16)v.y, (_Float16)v.z, (_Float16)v.w };
            *(half4v*)&dst[f * 4] = h;
        }
    } else {
        const int id = bi - 256;            // 512 blocks: 4b x 8h x 16 mtiles
        const int mt = id & 15, h = (id >> 4) & 7, b = id >> 7;
        const float4* Vf4 = (const float4*)V;
        for (int it = 0; it < 4; ++it) {
            const int ml = (t >> 4) + 16 * it;
            const int c4 = t & 15;
            float4 v = Vf4[(size_t)(b * 1024 + mt * 64 + ml) * 128 + h * 16 + c4];
            tile[c4 * 4 + 0][ml] = (_Float16)v.x;
            tile[c4 * 4 + 1][ml] = (_Float16)v.y;
            tile[c4 * 4 + 2][ml] = (_Float16)v.z;
            tile[c4 * 4 + 3][ml] = (_Float16)v.w;
        }
        __syncthreads();
        const int d = t >> 2, seg = t & 3;
        half8 o0 = *(half8*)&tile[d][seg * 16];
        half8 o1 = *(half8*)&tile[d][seg * 16 + 8];
        size_t obase = ((size_t)(b * 8 + h) * 64 + d) * 1024 + mt * 64 + seg * 16;
        *(half8*)&Vt[obase] = o0;
        *(half8*)&Vt[obase + 8] = o1;
    }
}

// ---------- qk_ln: s = K.Q^T per head via fp16 MFMA, LayerNorm over heads
// (lane-local: all 8 heads of a (l,m) element sit in the same lane/reg).
// Writes S[b][h][l][m] fp16. No masking here (softmax kernel masks by len).
__global__ __launch_bounds__(256) void qk_ln(
    const _Float16* __restrict__ K16, const _Float16* __restrict__ Q16,
    const float* __restrict__ gamma, const float* __restrict__ beta,
    _Float16* __restrict__ S)
{
    const int t = threadIdx.x;
    const int bi = blockIdx.x;          // 1024 = 4b x 64 ltiles x 4 msplit
    const int b = bi & 3;
    const int lt = (bi >> 2) & 63;
    const int ms = bi >> 8;             // 0..3
    const int wv = t >> 6, lane = t & 63;
    const int col = lane & 15, quad = lane >> 4;

    const _Float16* Kb = K16 + (size_t)b * 524288;
    const _Float16* Qb = Q16 + (size_t)b * 524288;
    const size_t krow = (size_t)(lt * 16 + col) * 512;

    float g[8], be[8];
    #pragma unroll
    for (int h = 0; h < 8; ++h) { g[h] = gamma[h]; be[h] = beta[h]; }

    for (int i = 0; i < 4; ++i) {
        const int m0 = (ms * 16 + wv * 4 + i) * 16;
        const size_t qrow = (size_t)(m0 + col) * 512;
        floatx4 c[8];
        #pragma unroll
        for (int h = 0; h < 8; ++h) {
            half8 a0 = *(const half8*)&Kb[krow + h * 64 + quad * 8];
            half8 a1 = *(const half8*)&Kb[krow + h * 64 + 32 + quad * 8];
            half8 b0 = *(const half8*)&Qb[qrow + h * 64 + quad * 8];
            half8 b1 = *(const half8*)&Qb[qrow + h * 64 + 32 + quad * 8];
            floatx4 z = {0.f, 0.f, 0.f, 0.f};
            z    = __builtin_amdgcn_mfma_f32_16x16x32_f16(a0, b0, z, 0, 0, 0);
            c[h] = __builtin_amdgcn_mfma_f32_16x16x32_f16(a1, b1, z, 0, 0, 0);
        }
        #pragma unroll
        for (int r = 0; r < 4; ++r) {
            float mu = 0.f;
            #pragma unroll
            for (int h = 0; h < 8; ++h) mu += c[h][r];
            mu *= 0.125f;
            float var = 0.f;
            #pragma unroll
            for (int h = 0; h < 8; ++h) { float dd = c[h][r] - mu; var += dd * dd; }
            var *= 0.125f;
            const float rs = 1.0f / sqrtf(var + 1e-5f);
            const int l = lt * 16 + quad * 4 + r;
            #pragma unroll
            for (int h = 0; h < 8; ++h) {
                float val = (c[h][r] - mu) * rs * g[h] + be[h];
                S[((size_t)(b * 8 + h) * 1024 + l) * 1024 + m0 + col] = (_Float16)val;
            }
        }
    }
}

// ---------- softmax_w: per-row masked softmax in-place (S -> p), fused
// column-sum (over l and h) partials -> atomics into wacc[b][m].
__global__ __launch_bounds__(256) void softmax_w(
    _Float16* __restrict__ S, const float* __restrict__ doc,
    float* __restrict__ wacc)
{
    __shared__ float cs[4][1024];
    const int t = threadIdx.x, wv = t >> 6, lane = t & 63;
    const int bi = blockIdx.x;            // 512 = 4b x 128 lgroups(8 l)
    const int b = bi & 3, lg = bi >> 2;
    const int len = (int)doc[b];

    float csum[16];
    #pragma unroll
    for (int j = 0; j < 16; ++j) csum[j] = 0.f;

    for (int k = 0; k < 16; ++k) {
        const int rr = wv * 16 + k;       // 64 rows/block: 8 l x 8 h
        const int h = rr & 7, li = rr >> 3;
        const int l = lg * 8 + li;
        const size_t base = ((size_t)(b * 8 + h) * 1024 + l) * 1024;
        if (l >= len) {                   // fully-masked row -> p = 0
            half8 z = {};
            *(half8*)&S[base + lane * 8] = z;
            *(half8*)&S[base + 512 + lane * 8] = z;
            continue;
        }
        half8 v1 = *(const half8*)&S[base + lane * 8];
        half8 v2 = *(const half8*)&S[base + 512 + lane * 8];
        float f1[8], f2[8];
        float mx = -INFINITY;
        #pragma unroll
        for (int j = 0; j < 8; ++j) { f1[j] = (float)v1[j]; mx = fmaxf(mx, f1[j]); }
        #pragma unroll
        for (int j = 0; j < 8; ++j) {
            const int m = 512 + lane * 8 + j;
            f2[j] = (m < len) ? (float)v2[j] : -INFINITY;
            mx = fmaxf(mx, f2[j]);
        }
        #pragma unroll
        for (int o = 1; o < 64; o <<= 1) mx = fmaxf(mx, __shfl_xor(mx, o));
        float e1[8], e2[8], sm = 0.f;
        #pragma unroll
        for (int j = 0; j < 8; ++j) { e1[j] = __expf(f1[j] - mx); sm += e1[j]; }
        #pragma unroll
        for (int j = 0; j < 8; ++j) {
            const int m = 512 + lane * 8 + j;
            e2[j] = (m < len) ? __expf(f2[j] - mx) : 0.f;
            sm += e2[j];
        }
        #pragma unroll
        for (int o = 1; o < 64; o <<= 1) sm += __shfl_xor(sm, o);
        const float inv = 1.0f / sm;
        half8 p1, p2;
        #pragma unroll
        for (int j = 0; j < 8; ++j) {
            float q1 = e1[j] * inv, q2 = e2[j] * inv;
            p1[j] = (_Float16)q1; p2[j] = (_Float16)q2;
            csum[j] += q1; csum[8 + j] += q2;
        }
        *(half8*)&S[base + lane * 8] = p1;
        *(half8*)&S[base + 512 + lane * 8] = p2;
    }
    #pragma unroll
    for (int j = 0; j < 8; ++j) {
        cs[wv][lane * 8 + j] = csum[j];
        cs[wv][512 + lane * 8 + j] = csum[8 + j];
    }
    __syncthreads();
    #pragma unroll
    for (int q = 0; q < 4; ++q) {
        const int mm = t + q * 256;
        float s = cs[0][mm] + cs[1][mm] + cs[2][mm] + cs[3][mm];
        atomicAdd(&wacc[b * 1024 + mm], s);
    }
}

// ---------- pv: O[b,l,h*64+d] = sum_m p[l,m] V[m,d] via fp16 MFMA
__global__ __launch_bounds__(256) void pv(
    const _Float16* __restrict__ P, const _Float16* __restrict__ Vt,
    float* __restrict__ out)
{
    const int t = threadIdx.x, wv = t >> 6, lane = t & 63;
    const int col = lane & 15, quad = lane >> 4;
    const int bi = blockIdx.x;            // 512 = 4b x 8h x 16 lblocks
    const int lb = bi & 15, h = (bi >> 4) & 7, b = bi >> 7;
    const int l0 = lb * 64 + wv * 16;
    const _Float16* Arow = P + ((size_t)(b * 8 + h) * 1024 + l0 + col) * 1024;
    const _Float16* Vb = Vt + (size_t)(b * 8 + h) * 65536;
    floatx4 acc[4] = {{0,0,0,0},{0,0,0,0},{0,0,0,0},{0,0,0,0}};
    for (int kc = 0; kc < 32; ++kc) {
        const int m0 = kc * 32 + quad * 8;
        half8 a = *(const half8*)&Arow[m0];
        #pragma unroll
        for (int dt = 0; dt < 4; ++dt) {
            half8 bf = *(const half8*)&Vb[(size_t)(dt * 16 + col) * 1024 + m0];
            acc[dt] = __builtin_amdgcn_mfma_f32_16x16x32_f16(a, bf, acc[dt], 0, 0, 0);
        }
    }
    #pragma unroll
    for (int r = 0; r < 4; ++r) {
        const int l = l0 + quad * 4 + r;
        float* orow = out + (size_t)(b * 1024 + l) * 512 + h * 64;
        #pragma unroll
        for (int dt = 0; dt < 4; ++dt)
            orow[dt * 16 + col] = acc[dt][r];
    }
}

// ---------- w finalize: w = softmax_m( (wacc/8)/len ), invalid -> 0
__global__ __launch_bounds__(256) void w_final(
    const float* __restrict__ wacc, const float* __restrict__ doc,
    float* __restrict__ wout)
{
    const int b = blockIdx.x;
    const int t = threadIdx.x;
    __shared__ float red[4];

    const float ds = doc[b];
    const int len = (int)ds;

    float v[4];
    float mx = -INFINITY;
    #pragma unroll
    for (int i = 0; i < 4; ++i) {
        const int m = t + 256 * i;
        const float raw = wacc[b * L_ + m];
        v[i] = (m < len) ? (raw * 0.125f) / ds : -INFINITY;
        mx = fmaxf(mx, v[i]);
    }
    #pragma unroll
    for (int off = 1; off < 64; off <<= 1) mx = fmaxf(mx, __shfl_xor(mx, off));
    if ((t & 63) == 0) red[t >> 6] = mx;
    __syncthreads();
    mx = fmaxf(fmaxf(red[0], red[1]), fmaxf(red[2], red[3]));

    float e[4];
    float sm = 0.f;
    #pragma unroll
    for (int i = 0; i < 4; ++i) {
        e[i] = (v[i] != -INFINITY) ? __expf(v[i] - mx) : 0.f;
        sm += e[i];
    }
    #pragma unroll
    for (int off = 1; off < 64; off <<= 1) sm += __shfl_xor(sm, off);
    __syncthreads();
    if ((t & 63) == 0) red[t >> 6] = sm;
    __syncthreads();
    sm = red[0] + red[1] + red[2] + red[3];
    const float inv = (sm > 0.f) ? 1.0f / sm : 0.f;

    #pragma unroll
    for (int i = 0; i < 4; ++i)
        wout[b * L_ + t + 256 * i] = e[i] * inv;
}

extern "C" void kernel_launch(void* const* d_in, const int* in_sizes, int n_in,
                              void* d_out, int out_size, void* d_ws, size_t ws_size,
                              hipStream_t stream)
{
    const float* K     = (const float*)d_in[0];
    const float* Q     = (const float*)d_in[1];
    const float* V     = (const float*)d_in[2];
    const float* doc   = (const float*)d_in[3];
    const float* gamma = (const float*)d_in[4];
    const float* beta  = (const float*)d_in[5];
    // d_in[6]/d_in[7] (masks) derivable from doc_sizes.

    float* out  = (float*)d_out;
    float* wout = out + (size_t)4 * L_ * D_;

    // workspace layout (halves): S 32Mi, K16 2Mi, Q16 2Mi, Vt 2Mi, then wacc
    _Float16* S   = (_Float16*)d_ws;
    _Float16* K16 = S + (size_t)33554432;     // 64 MB
    _Float16* Q16 = K16 + 2097152;            // +4 MB
    _Float16* Vt  = Q16 + 2097152;            // +4 MB
    float*    wacc = (float*)(Vt + 2097152);  // +4 MB, 16 KB used

    hipMemsetAsync(wacc, 0, 4096 * sizeof(float), stream);
    prep     <<<dim3(768),  dim3(256), 0, stream>>>(K, Q, V, K16, Q16, Vt);
    qk_ln    <<<dim3(1024), dim3(256), 0, stream>>>(K16, Q16, gamma, beta, S);
    softmax_w<<<dim3(512),  dim3(256), 0, stream>>>(S, doc, wacc);
    pv       <<<dim3(512),  dim3(256), 0, stream>>>(S, Vt, out);
    w_final  <<<dim3(4),    dim3(256), 0, stream>>>(wacc, doc, wout);
}

// Round 3
// 202.206 us; speedup vs baseline: 4.1002x; 1.0281x over previous
//
#include <hip/hip_runtime.h>
#include <math.h>

// B=4, L=1024, D=512, H=8, d=64
#define L_ 1024
#define D_ 512

typedef _Float16 half8 __attribute__((ext_vector_type(8)));
typedef _Float16 half4v __attribute__((ext_vector_type(4)));
typedef _Float16 half2v __attribute__((ext_vector_type(2)));
typedef float floatx4 __attribute__((ext_vector_type(4)));

#define LDS_PITCH 264   // halves per (h,l) row in qk_ln staging (16B-aligned, bank-skewed)

// ---------- prep: K,Q -> fp16 straight; V -> fp16 transposed Vt[b][h][d][m]
__global__ __launch_bounds__(256) void prep(
    const float* __restrict__ K, const float* __restrict__ Q,
    const float* __restrict__ V,
    _Float16* __restrict__ K16, _Float16* __restrict__ Q16,
    _Float16* __restrict__ Vt)
{
    __shared__ _Float16 tile[64][72];
    const int t = threadIdx.x;
    const int bi = blockIdx.x;
    if (bi < 256) {
        for (int it = 0; it < 16; ++it) {
            size_t f = (size_t)bi * 4096 + it * 256 + t;
            const float4* src; _Float16* dst;
            if (f < 524288) { src = (const float4*)K; dst = K16; }
            else            { src = (const float4*)Q; dst = Q16; f -= 524288; }
            float4 v = src[f];
            half4v h = { (_Float16)v.x, (_Float16)v.y, (_Float16)v.z, (_Float16)v.w };
            *(half4v*)&dst[f * 4] = h;
        }
    } else {
        const int id = bi - 256;            // 512 blocks: 4b x 8h x 16 mtiles
        const int mt = id & 15, h = (id >> 4) & 7, b = id >> 7;
        const float4* Vf4 = (const float4*)V;
        for (int it = 0; it < 4; ++it) {
            const int ml = (t >> 4) + 16 * it;
            const int c4 = t & 15;
            float4 v = Vf4[(size_t)(b * 1024 + mt * 64 + ml) * 128 + h * 16 + c4];
            tile[c4 * 4 + 0][ml] = (_Float16)v.x;
            tile[c4 * 4 + 1][ml] = (_Float16)v.y;
            tile[c4 * 4 + 2][ml] = (_Float16)v.z;
            tile[c4 * 4 + 3][ml] = (_Float16)v.w;
        }
        __syncthreads();
        const int d = t >> 2, seg = t & 3;
        half8 o0 = *(half8*)&tile[d][seg * 16];
        half8 o1 = *(half8*)&tile[d][seg * 16 + 8];
        size_t obase = ((size_t)(b * 8 + h) * 64 + d) * 1024 + mt * 64 + seg * 16;
        *(half8*)&Vt[obase] = o0;
        *(half8*)&Vt[obase + 8] = o1;
    }
}

// ---------- qk_ln: e = exp(LN(K.Q^T) - M) via fp16 MFMA, masked, stored
// coalesced to S[b][h][l][m] via LDS; per-row partial sums -> spart.
// M = max_h(2.8285*|gamma_h|+|beta_h|) is a data-independent LN output bound,
// so no per-row max pass is needed (exp never overflows).
__global__ __launch_bounds__(256) void qk_ln(
    const _Float16* __restrict__ K16, const _Float16* __restrict__ Q16,
    const float* __restrict__ gamma, const float* __restrict__ beta,
    const float* __restrict__ doc,
    _Float16* __restrict__ S, float* __restrict__ spart)
{
    __shared__ _Float16 se[8 * 16 * LDS_PITCH];   // 67584 B -> 2 blocks/CU

    const int t  = threadIdx.x;
    const int bi = blockIdx.x;              // 1024 = 4b x 64 lt x 4 q
    const int b  = bi & 3;
    const int lt = (bi >> 2) & 63;
    const int q  = bi >> 8;
    const int wv = t >> 6, lane = t & 63;
    const int col = lane & 15, quad = lane >> 4;
    const int len = (int)doc[b];
    const int lbase = lt * 16;

    float g[8], be[8], M = 0.f;
    #pragma unroll
    for (int h = 0; h < 8; ++h) {
        g[h] = gamma[h]; be[h] = beta[h];
        M = fmaxf(M, 2.8285f * fabsf(g[h]) + fabsf(be[h]));
    }

    const _Float16* Kb = K16 + (size_t)b * 524288;
    const _Float16* Qb = Q16 + (size_t)b * 524288;
    const size_t krow = (size_t)(lbase + col) * 512;

    half8 a0[8], a1[8];
    #pragma unroll
    for (int h = 0; h < 8; ++h) {
        a0[h] = *(const half8*)&Kb[krow + h * 64 + quad * 8];
        a1[h] = *(const half8*)&Kb[krow + h * 64 + 32 + quad * 8];
    }

    float sum[8][4];
    #pragma unroll
    for (int h = 0; h < 8; ++h)
        #pragma unroll
        for (int r = 0; r < 4; ++r) sum[h][r] = 0.f;

    for (int mt = 0; mt < 4; ++mt) {
        const int m0 = q * 256 + wv * 64 + mt * 16;
        const size_t qrow = (size_t)(m0 + col) * 512;
        floatx4 c[8];
        #pragma unroll
        for (int h = 0; h < 8; ++h) {
            half8 b0 = *(const half8*)&Qb[qrow + h * 64 + quad * 8];
            half8 b1 = *(const half8*)&Qb[qrow + h * 64 + 32 + quad * 8];
            floatx4 z = {0.f, 0.f, 0.f, 0.f};
            z    = __builtin_amdgcn_mfma_f32_16x16x32_f16(a0[h], b0, z, 0, 0, 0);
            c[h] = __builtin_amdgcn_mfma_f32_16x16x32_f16(a1[h], b1, c[h] = z, 0, 0, 0);
        }
        const bool mok = (m0 + col) < len;
        #pragma unroll
        for (int r = 0; r < 4; ++r) {
            const int l = lbase + quad * 4 + r;
            float mu = 0.f;
            #pragma unroll
            for (int h = 0; h < 8; ++h) mu += c[h][r];
            mu *= 0.125f;
            float var = 0.f;
            #pragma unroll
            for (int h = 0; h < 8; ++h) { float dd = c[h][r] - mu; var += dd * dd; }
            var *= 0.125f;
            const float rs = 1.0f / sqrtf(var + 1e-5f);
            const bool keep = mok && (l < len);
            #pragma unroll
            for (int h = 0; h < 8; ++h) {
                float e = 0.f;
                if (keep) {
                    float val = (c[h][r] - mu) * rs * g[h] + be[h];
                    e = __expf(val - M);
                }
                sum[h][r] += e;
                se[(h * 16 + quad * 4 + r) * LDS_PITCH + wv * 64 + mt * 16 + col] =
                    (_Float16)e;
            }
        }
    }

    // reduce row partial sums over the 16 col-lanes of each quad
    #pragma unroll
    for (int h = 0; h < 8; ++h)
        #pragma unroll
        for (int r = 0; r < 4; ++r) {
            float s = sum[h][r];
            s += __shfl_xor(s, 1); s += __shfl_xor(s, 2);
            s += __shfl_xor(s, 4); s += __shfl_xor(s, 8);
            sum[h][r] = s;
        }
    if (col == 0) {
        #pragma unroll
        for (int h = 0; h < 8; ++h)
            #pragma unroll
            for (int r = 0; r < 4; ++r)
                spart[((size_t)((b * 8 + h) * 1024 + lbase + quad * 4 + r)) * 16
                      + q * 4 + wv] = sum[h][r];
    }
    __syncthreads();

    // coalesced store: 128 rows x 512 B
    for (int it = 0; it < 16; ++it) {
        const int rr = it * 8 + (t >> 5);
        const int h = rr >> 4, l = rr & 15;
        half8 v = *(half8*)&se[rr * LDS_PITCH + (t & 31) * 8];
        *(half8*)&S[((size_t)((b * 8 + h) * 1024 + lbase + l)) * 1024
                    + q * 256 + (t & 31) * 8] = v;
    }
}

// ---------- stats_reduce: inv[row] = 1/sum(e) (0 for padded rows)
__global__ __launch_bounds__(256) void stats_reduce(
    const float* __restrict__ spart, const float* __restrict__ doc,
    float* __restrict__ inv)
{
    const int i = blockIdx.x * 256 + threadIdx.x;   // 32768 rows
    const int l = i & 1023;
    const int b = i >> 13;
    const int len = (int)doc[b];
    float s = 0.f;
    #pragma unroll
    for (int j = 0; j < 16; ++j) s += spart[(size_t)i * 16 + j];
    inv[i] = (l < len && s > 0.f) ? 1.0f / s : 0.f;
}

// ---------- pv: p = e*inv (lane-scalar inv), PV MFMA, fused w colsum
__global__ __launch_bounds__(256) void pv(
    const _Float16* __restrict__ S, const _Float16* __restrict__ Vt,
    const float* __restrict__ invp,
    float* __restrict__ out, float* __restrict__ wacc)
{
    __shared__ float cs[1024];
    const int t = threadIdx.x, wv = t >> 6, lane = t & 63;
    const int col = lane & 15, quad = lane >> 4;
    const int bi = blockIdx.x;            // 512 = 4b x 8h x 16 lb
    const int lb = bi & 15, h = (bi >> 4) & 7, b = bi >> 7;
    const int l0 = lb * 64 + wv * 16;

    #pragma unroll
    for (int i = 0; i < 4; ++i) cs[t + 256 * i] = 0.f;
    __syncthreads();

    const _Float16* Arow = S + ((size_t)(b * 8 + h) * 1024 + l0 + col) * 1024;
    const _Float16* Vb = Vt + (size_t)(b * 8 + h) * 65536;
    const float inv = invp[(size_t)(b * 8 + h) * 1024 + l0 + col];

    floatx4 acc[4] = {{0,0,0,0},{0,0,0,0},{0,0,0,0},{0,0,0,0}};
    for (int kc = 0; kc < 32; ++kc) {
        const int m0 = kc * 32 + quad * 8;
        half8 e = *(const half8*)&Arow[m0];
        half8 a;
        #pragma unroll
        for (int j = 0; j < 8; ++j) a[j] = (_Float16)((float)e[j] * inv);

        // colsum over the 16 rows (col-lanes) of this quad, packed fp16
        #pragma unroll
        for (int u = 0; u < 4; ++u) {
            half2v p2 = { a[2 * u], a[2 * u + 1] };
            int bits = *(int*)&p2;
            #pragma unroll
            for (int o = 1; o < 16; o <<= 1) {
                int ob = __shfl_xor(bits, o);
                half2v po = *(half2v*)&ob;
                half2v pc = *(half2v*)&bits;
                pc[0] = pc[0] + po[0]; pc[1] = pc[1] + po[1];
                bits = *(int*)&pc;
            }
            if (col == 0) {
                half2v pc = *(half2v*)&bits;
                atomicAdd(&cs[m0 + 2 * u],     (float)pc[0]);
                atomicAdd(&cs[m0 + 2 * u + 1], (float)pc[1]);
            }
        }
        #pragma unroll
        for (int dt = 0; dt < 4; ++dt) {
            half8 bf = *(const half8*)&Vb[(size_t)(dt * 16 + col) * 1024 + m0];
            acc[dt] = __builtin_amdgcn_mfma_f32_16x16x32_f16(a, bf, acc[dt], 0, 0, 0);
        }
    }
    #pragma unroll
    for (int r = 0; r < 4; ++r) {
        const int l = l0 + quad * 4 + r;
        float* orow = out + (size_t)(b * 1024 + l) * 512 + h * 64;
        #pragma unroll
        for (int dt = 0; dt < 4; ++dt)
            orow[dt * 16 + col] = acc[dt][r];
    }
    __syncthreads();
    #pragma unroll
    for (int i = 0; i < 4; ++i) {
        const int m = t + 256 * i;
        atomicAdd(&wacc[b * 1024 + m], cs[m]);
    }
}

// ---------- w finalize: w = softmax_m( (wacc/8)/len ), invalid -> 0
__global__ __launch_bounds__(256) void w_final(
    const float* __restrict__ wacc, const float* __restrict__ doc,
    float* __restrict__ wout)
{
    const int b = blockIdx.x;
    const int t = threadIdx.x;
    __shared__ float red[4];

    const float ds = doc[b];
    const int len = (int)ds;

    float v[4];
    float mx = -INFINITY;
    #pragma unroll
    for (int i = 0; i < 4; ++i) {
        const int m = t + 256 * i;
        const float raw = wacc[b * L_ + m];
        v[i] = (m < len) ? (raw * 0.125f) / ds : -INFINITY;
        mx = fmaxf(mx, v[i]);
    }
    #pragma unroll
    for (int off = 1; off < 64; off <<= 1) mx = fmaxf(mx, __shfl_xor(mx, off));
    if ((t & 63) == 0) red[t >> 6] = mx;
    __syncthreads();
    mx = fmaxf(fmaxf(red[0], red[1]), fmaxf(red[2], red[3]));

    float e[4];
    float sm = 0.f;
    #pragma unroll
    for (int i = 0; i < 4; ++i) {
        e[i] = (v[i] != -INFINITY) ? __expf(v[i] - mx) : 0.f;
        sm += e[i];
    }
    #pragma unroll
    for (int off = 1; off < 64; off <<= 1) sm += __shfl_xor(sm, off);
    __syncthreads();
    if ((t & 63) == 0) red[t >> 6] = sm;
    __syncthreads();
    sm = red[0] + red[1] + red[2] + red[3];
    const float inv = (sm > 0.f) ? 1.0f / sm : 0.f;

    #pragma unroll
    for (int i = 0; i < 4; ++i)
        wout[b * L_ + t + 256 * i] = e[i] * inv;
}

extern "C" void kernel_launch(void* const* d_in, const int* in_sizes, int n_in,
                              void* d_out, int out_size, void* d_ws, size_t ws_size,
                              hipStream_t stream)
{
    const float* K     = (const float*)d_in[0];
    const float* Q     = (const float*)d_in[1];
    const float* V     = (const float*)d_in[2];
    const float* doc   = (const float*)d_in[3];
    const float* gamma = (const float*)d_in[4];
    const float* beta  = (const float*)d_in[5];

    float* out  = (float*)d_out;
    float* wout = out + (size_t)4 * L_ * D_;

    _Float16* S    = (_Float16*)d_ws;               // 64 MB (e-values)
    _Float16* K16  = S + (size_t)33554432;          // +4 MB
    _Float16* Q16  = K16 + 2097152;                 // +4 MB
    _Float16* Vt   = Q16 + 2097152;                 // +4 MB
    float*    spart = (float*)(Vt + 2097152);       // 2 MB (32768 x 16)
    float*    invp  = spart + 524288;               // 128 KB
    float*    wacc  = invp + 32768;                 // 16 KB

    hipMemsetAsync(wacc, 0, 4096 * sizeof(float), stream);
    prep        <<<dim3(768),  dim3(256), 0, stream>>>(K, Q, V, K16, Q16, Vt);
    qk_ln       <<<dim3(1024), dim3(256), 0, stream>>>(K16, Q16, gamma, beta, doc, S, spart);
    stats_reduce<<<dim3(128),  dim3(256), 0, stream>>>(spart, doc, invp);
    pv          <<<dim3(512),  dim3(256), 0, stream>>>(S, Vt, invp, out, wacc);
    w_final     <<<dim3(4),    dim3(256), 0, stream>>>(wacc, doc, wout);
}